// Round 1
// baseline (131.312 us; speedup 1.0000x reference)
//
#include <hip/hip_runtime.h>
#include <stdint.h>

// ---------------------------------------------------------------------------
// VCSMC step on MI355X. Bit-exact JAX threefry RNG (partitionable semantics).
// R5: FULL FUSION. All four phases (resample+RNG, logits, Lorig site pass,
// merged site pass, combine) are per-particle-local -> one kernel,
// 256 blocks x 1024 threads (one thread per site). Eliminates 3 dispatch
// dependencies, the Lpart/eslw/enlm/used global round-trips, and the
// grid-wide barriers. All arithmetic and reduction trees replicate the
// previous 4-kernel version bit-exactly (same intrinsics, same shfl trees,
// same site->wave grouping, same left-assoc combine order).
//   expm collapse: Q^2 = -Q  =>  expm(b*Q) = I + (1-e^-b) Q (exact).
// ---------------------------------------------------------------------------

#define TF_ROT(x0,x1,r) { x0 += x1; x1 = ((x1<<(r))|(x1>>(32-(r)))); x1 ^= x0; }

__host__ __device__ inline void tf2x32(uint32_t k0, uint32_t k1,
                                       uint32_t x0, uint32_t x1,
                                       uint32_t& o0, uint32_t& o1) {
  uint32_t ks2 = k0 ^ k1 ^ 0x1BD11BDAu;
  x0 += k0; x1 += k1;
  TF_ROT(x0,x1,13) TF_ROT(x0,x1,15) TF_ROT(x0,x1,26) TF_ROT(x0,x1,6)
  x0 += k1; x1 += ks2 + 1u;
  TF_ROT(x0,x1,17) TF_ROT(x0,x1,29) TF_ROT(x0,x1,16) TF_ROT(x0,x1,24)
  x0 += ks2; x1 += k0 + 2u;
  TF_ROT(x0,x1,13) TF_ROT(x0,x1,15) TF_ROT(x0,x1,26) TF_ROT(x0,x1,6)
  x0 += k0; x1 += k1 + 3u;
  TF_ROT(x0,x1,17) TF_ROT(x0,x1,29) TF_ROT(x0,x1,16) TF_ROT(x0,x1,24)
  x0 += k1; x1 += ks2 + 4u;
  TF_ROT(x0,x1,13) TF_ROT(x0,x1,15) TF_ROT(x0,x1,26) TF_ROT(x0,x1,6)
  x0 += ks2; x1 += k0 + 5u;
  o0 = x0; o1 = x1;
}

struct Keys {
  uint32_t kres0, kres1;
  uint32_t k2i0, k2i1;
  uint32_t k1o0, k1o1;
  uint32_t k2o0, k2o1;
  uint32_t ku10, ku11;
  uint32_t ku20, ku21;
};

__device__ inline uint32_t rb_fold(uint32_t k0, uint32_t k1, uint32_t i) {
  uint32_t o0, o1;
  tf2x32(k0, k1, 0u, i, o0, o1);
  return o0 ^ o1;
}

__device__ inline float u01f(uint32_t b) {
  return __uint_as_float((b >> 9) | 0x3F800000u) - 1.0f;
}

#define TINYF 1.17549435e-38f

// ---------------------------------------------------------------------------
// One block per output particle k. 1024 threads = 1024 sites.
// ---------------------------------------------------------------------------
__global__ __launch_bounds__(1024) void k_all(
    const float* __restrict__ logw, const float* __restrict__ b1r,
    const float* __restrict__ b2r, const int* __restrict__ lc,
    const float* __restrict__ emb, const float* __restrict__ lfg,
    const float* __restrict__ logpi, const float* __restrict__ site,
    const float* __restrict__ Wstat, const float* __restrict__ Wsite,
    const float* __restrict__ ldf, float* __restrict__ out, Keys kk) {
  int k = blockIdx.x, tid = threadIdx.x;
  __shared__ float sval[256];
  __shared__ int   sidx[256];
  __shared__ float enl[64];          // original-subtree exp-logits [t][a]
  __shared__ float sredt[256];       // Lorig wave partials [t][wave] = t*16+w
  __shared__ float sredm[16];        // merged wave partials [wave]
  __shared__ float sh_m[4];          // merged-node exp-logits
  __shared__ float sh_w1, sh_w2, sh_cw;
  __shared__ int   sh_i1, sh_i2;

  // ---- Phase 1: Gumbel-max categorical resampling (threads 0..255) ----
  if (tid < 256) {
    uint32_t b = rb_fold(kk.kres0, kk.kres1, (uint32_t)(k * 256 + tid));
    float u = fmaxf(TINYF, u01f(b) + TINYF);
    float g = -logf(-logf(u));            // precise: discrete decision
    sval[tid] = g + logw[tid];
    sidx[tid] = tid;
  }
  __syncthreads();
  for (int st = 128; st > 0; st >>= 1) {
    if (tid < st) {
      float va = sval[tid], vb = sval[tid + st];
      int ia = sidx[tid], ib = sidx[tid + st];
      if (vb > va || (vb == va && ib < ia)) { sval[tid] = vb; sidx[tid] = ib; }
    }
    __syncthreads();
  }
  int p = sidx[0];

  // ---- Phase 2 (all concurrent, one barrier after):
  //   all threads : per-site exp(site logits) into registers (s = tid)
  //   tid 0..3    : pair RNG (recomputed, deterministic) + merged exp-logits
  //   tid 4       : branch RNG + prior/topo scalar constant
  //   tid 64..127 : original-subtree exp-logits enl[64]
  float es0, es1, es2, es3;
  {
    int s = tid;
    float a0 = 0.f, a1 = 0.f, a2 = 0.f, a3 = 0.f;
#pragma unroll
    for (int c = 0; c < 16; c++) {
      float sc = site[s * 16 + c];
      a0 += sc * Wsite[c * 4 + 0];
      a1 += sc * Wsite[c * 4 + 1];
      a2 += sc * Wsite[c * 4 + 2];
      a3 += sc * Wsite[c * 4 + 3];
    }
    es0 = __expf(a0); es1 = __expf(a1); es2 = __expf(a2); es3 = __expf(a3);
  }

  if (tid >= 64 && tid < 128) {
    int q = tid - 64;
    int t = q >> 2, a = q & 3;
    const float4* e4 = (const float4*)(emb + ((size_t)p * 16 + t) * 64);
    float acc = 0.0f;
#pragma unroll
    for (int d4 = 0; d4 < 16; d4++) {
      float4 e = e4[d4];
      acc += e.x * Wstat[(d4 * 4 + 0) * 4 + a] + e.y * Wstat[(d4 * 4 + 1) * 4 + a] +
             e.z * Wstat[(d4 * 4 + 2) * 4 + a] + e.w * Wstat[(d4 * 4 + 3) * 4 + a];
    }
    enl[q] = __expf(acc);
  }

  if (tid < 5) {
    // pair RNG -- identical arithmetic on threads 0..4 (deterministic)
    uint32_t i = rb_fold(kk.k2i0, kk.k2i1, (uint32_t)k) & 15u;
    uint32_t h = rb_fold(kk.k1o0, kk.k1o1, (uint32_t)k) % 15u;
    uint32_t l = rb_fold(kk.k2o0, kk.k2o1, (uint32_t)k) % 15u;
    uint32_t off = 1u + (h + l) % 15u;
    uint32_t j = (i + off) & 15u;
    int i1 = (int)(i < j ? i : j);
    int i2 = (int)(i < j ? j : i);

    if (tid < 4) {
      if (tid == 0) { sh_i1 = i1; sh_i2 = i2; }
      int a = tid;
      const float* e1p = emb + ((size_t)p * 16 + i1) * 64;
      const float* e2p = emb + ((size_t)p * 16 + i2) * 64;
      float acc = 0.0f;
      for (int d = 0; d < 64; d++) acc += 0.5f * (e1p[d] + e2p[d]) * Wstat[d * 4 + a];
      sh_m[a] = __expf(acc);
    } else {
      // tid == 4: branch lengths + scalar constant cw
      const float SUBR = 1.0f - 1e-6f;
      float u1 = fmaxf(1e-6f, u01f(rb_fold(kk.ku10, kk.ku11, (uint32_t)k)) * SUBR + 1e-6f);
      float u2 = fmaxf(1e-6f, u01f(rb_fold(kk.ku20, kk.ku21, (uint32_t)k)) * SUBR + 1e-6f);
      float b1 = -0.1f * logf(u1);
      float b2 = -0.1f * logf(u2);
      sh_w1 = 1.0f - expf(-b1);
      sh_w2 = 1.0f - expf(-b2);

      float sb = b1 + b2;
      for (int r = 0; r < 16; r++) sb += b1r[p * 16 + r] + b2r[p * 16 + r];
      float prior = -sb / 0.1f - 34.0f * logf(0.1f);

      float topo_sum = 0.0f; int cnt = 0;
      for (int t = 0; t < 15; t++) {
        int lct;
        if (t == i1)      lct = lc[p * 16 + i1] + lc[p * 16 + i2];
        else if (t == i2) lct = lc[p * 16 + 15];
        else              lct = lc[p * 16 + t];
        int ti = 2 * lct - 3; ti = ti < 0 ? 0 : (ti > 63 ? 63 : ti);
        if (lct >= 2) topo_sum -= ldf[ti];
        if (lct > 1) cnt++;
      }
      float log_v_minus = logf(fmaxf((float)cnt, 1.0f));
      float log_v_plus = logf(120.0f);
      sh_cw = prior + topo_sum - logpi[p] + log_v_minus - log_v_plus;
    }
  }
  __syncthreads();

  // ---- Phase 3: Lorig site pass (log2 domain), s = tid, loop over t ----
  const float* base = lfg + (size_t)p * 65536;
  int s = tid;
  float acc[16];
#pragma unroll
  for (int t = 0; t < 16; t++) {
    float4 lf = *(const float4*)(base + t * 4096 + s * 4);
    float w0 = enl[t * 4 + 0] * es0, w1 = enl[t * 4 + 1] * es1;
    float w2 = enl[t * 4 + 2] * es2, w3 = enl[t * 4 + 3] * es3;
    float S1 = w0 + w1 + w2 + w3;
    float S2 = __expf(lf.x) * w0 + __expf(lf.y) * w1 +
               __expf(lf.z) * w2 + __expf(lf.w) * w3;
    acc[t] = __log2f(S2) - __log2f(S1);
  }
  // per-t wave reductions: wave w covers sites [64w, 64w+63] (same grouping
  // as old sblk*4+subwave layout -> identical FP tree)
#pragma unroll
  for (int t = 0; t < 16; t++) {
    float v = acc[t];
    for (int o = 32; o > 0; o >>= 1) v += __shfl_down(v, o, 64);
    if ((tid & 63) == 0) sredt[t * 16 + (tid >> 6)] = v;
  }

  // ---- Phase 4: merged-node site term (identical to old k_fin body) ----
  {
    int i1 = sh_i1, i2 = sh_i2;
    float w1 = sh_w1, w2 = sh_w2;
    float om1 = 1.0f - w1, om2 = 1.0f - w2;
    float m0 = sh_m[0], m1 = sh_m[1], m2 = sh_m[2], m3 = sh_m[3];
    float t0 = m0 * es0, t1 = m1 * es1, t2 = m2 * es2, t3 = m3 * es3;
    float T = t0 + t1 + t2 + t3;
    float invT = 1.0f / T;
    float4 lf1 = *(const float4*)(base + i1 * 4096 + s * 4);
    float4 lf2 = *(const float4*)(base + i2 * 4096 + s * 4);
    float f10 = __expf(lf1.x), f11 = __expf(lf1.y), f12 = __expf(lf1.z), f13 = __expf(lf1.w);
    float f20 = __expf(lf2.x), f21 = __expf(lf2.y), f22 = __expf(lf2.z), f23 = __expf(lf2.w);
    float dot1 = (t0 * f10 + t1 * f11 + t2 * f12 + t3 * f13) * invT;
    float dot2 = (t0 * f20 + t1 * f21 + t2 * f22 + t3 * f23) * invT;
    float n0 = __logf(om1 * f10 + w1 * dot1 + 1e-30f) + __logf(om2 * f20 + w2 * dot2 + 1e-30f);
    float n1 = __logf(om1 * f11 + w1 * dot1 + 1e-30f) + __logf(om2 * f21 + w2 * dot2 + 1e-30f);
    float n2 = __logf(om1 * f12 + w1 * dot1 + 1e-30f) + __logf(om2 * f22 + w2 * dot2 + 1e-30f);
    float n3 = __logf(om1 * f13 + w1 * dot1 + 1e-30f) + __logf(om2 * f23 + w2 * dot2 + 1e-30f);
    float S2 = __expf(n0) * t0 + __expf(n1) * t1 + __expf(n2) * t2 + __expf(n3) * t3;
    float tot = __logf(S2) - __logf(T);

    for (int o = 32; o > 0; o >>= 1) tot += __shfl_down(tot, o, 64);
    if ((tid & 63) == 0) sredm[tid >> 6] = tot;
  }
  __syncthreads();

  // ---- Phase 5: final combine (one wave; identical tree to old k_fin) ----
  if (tid < 64) {
    int t = tid & 15, sb = tid >> 4;
    int i1 = sh_i1, i2 = sh_i2;
    // Lpart[p][sblk][t] equivalent: left-assoc sum of the 4 subwave partials
    float s4 = sredt[t * 16 + sb * 4 + 0] + sredt[t * 16 + sb * 4 + 1] +
               sredt[t * 16 + sb * 4 + 2] + sredt[t * 16 + sb * 4 + 3];
    float Lv = s4 * 0.69314718056f;       // ln2
    float coef = (t == i1 || t == i2) ? 0.0f : 1.0f;
    float v = coef * Lv;
    if (tid < 16) v += sredm[tid];
    for (int o = 32; o > 0; o >>= 1) v += __shfl_down(v, o, 64);
    if (tid == 0) out[k] = sh_cw + v;
  }
}

// ---------------------------------------------------------------------------
extern "C" void kernel_launch(void* const* d_in, const int* in_sizes, int n_in,
                              void* d_out, int out_size, void* d_ws, size_t ws_size,
                              hipStream_t stream) {
  const float* logw  = (const float*)d_in[0];
  const float* b1r   = (const float*)d_in[1];
  const float* b2r   = (const float*)d_in[2];
  const int*   lc    = (const int*)d_in[3];
  const float* emb   = (const float*)d_in[4];
  const float* lfg   = (const float*)d_in[5];
  const float* logpi = (const float*)d_in[6];
  const float* site  = (const float*)d_in[7];
  const float* Wstat = (const float*)d_in[8];
  const float* Wsite = (const float*)d_in[9];
  const float* ldf   = (const float*)d_in[10];

  uint32_t S0[5], S1[5];
  for (uint32_t i = 0; i < 5; i++) tf2x32(0u, 42u, 0u, i, S0[i], S1[i]);
  Keys kk;
  kk.kres0 = S0[0]; kk.kres1 = S1[0];
  kk.ku10  = S0[3]; kk.ku11  = S1[3];
  kk.ku20  = S0[4]; kk.ku21  = S1[4];
  {
    uint32_t a0, a1, b0, b1;
    tf2x32(S0[1], S1[1], 0u, 0u, a0, a1);
    tf2x32(S0[1], S1[1], 0u, 1u, b0, b1);
    (void)a0; (void)a1;
    kk.k2i0 = b0; kk.k2i1 = b1;
  }
  {
    uint32_t a0, a1, b0, b1;
    tf2x32(S0[2], S1[2], 0u, 0u, a0, a1);
    tf2x32(S0[2], S1[2], 0u, 1u, b0, b1);
    kk.k1o0 = a0; kk.k1o1 = a1;
    kk.k2o0 = b0; kk.k2o1 = b1;
  }

  k_all<<<256, 1024, 0, stream>>>(logw, b1r, b2r, lc, emb, lfg, logpi,
                                  site, Wstat, Wsite, ldf, (float*)d_out, kk);
}